// Round 3
// baseline (313.585 us; speedup 1.0000x reference)
//
#include <hip/hip_runtime.h>

// Problem constants
#define HW 65536            // 256*256
#define GROUPS 16384        // float4 groups per plane
#define NMASK_CH 9
#define NKP_CH 23
#define NPARTS 8
#define NB 32

// Workspace layout (ints):
//   [0, 1536)            mask half-plane partials: (b*8+p)*2+half -> *3 {cnt,sx,sy}
//   [1536, 1536+24576)   kp partials: 1536 + (b*32+c)*24 + p*3 + {cnt,sx,sy}
#define KP_OFF 1536

typedef float vf4 __attribute__((ext_vector_type(4)));

// ---------------------------------------------------------------------------
// Fused stats kernel, grid = 1536 blocks x 256 threads (6 blocks/CU).
//   blocks [0,1024):    kp chunk  (b = bid>>5, c = bid&31), 2 float4/thread,
//                       all 23 channels -> 8 part sums -> 24 integrals
//   blocks [1024,1536): mask half-plane (id = bid-1024: b = id>>4,
//                       p = (id>>1)&7, half = id&1), 32 float4/thread
// Per-block partials written to ws; no atomics, no zero-init needed.
// Plain (cached) loads — nt hint removed for A/B vs R2.
// ---------------------------------------------------------------------------
__global__ __launch_bounds__(256) void stats_kernel(
    const float* __restrict__ masks, const float* __restrict__ kp,
    int* __restrict__ stats) {
    const int tid = threadIdx.x;
    const int bid = blockIdx.x;
    const int wave = tid >> 6;
    __shared__ int sh[4][NPARTS * 3];

    if (bid >= 1024) {
        // ---- mask path: half a plane per block ----
        const int id = bid - 1024;
        const int b = id >> 4, p = (id >> 1) & 7, half = id & 1;
        const float* plane = masks + ((size_t)b * NMASK_CH + 1 + p) * HW;
        const vf4* pl4 = (const vf4*)plane;
        int cnt = 0, sx = 0, sy = 0;
        const int gbase = half * 8192;
#pragma unroll 8
        for (int j = 0; j < 32; ++j) {
            const int g = gbase + tid + j * 256;
            const vf4 v = pl4[g];
            const int base = g * 4;
            const int h = base >> 8, w0 = base & 255;
            if (v.x > 0.5f) { cnt++; sx += h; sy += w0; }
            if (v.y > 0.5f) { cnt++; sx += h; sy += w0 + 1; }
            if (v.z > 0.5f) { cnt++; sx += h; sy += w0 + 2; }
            if (v.w > 0.5f) { cnt++; sx += h; sy += w0 + 3; }
        }
#pragma unroll
        for (int off = 32; off; off >>= 1) {
            cnt += __shfl_down(cnt, off);
            sx  += __shfl_down(sx, off);
            sy  += __shfl_down(sy, off);
        }
        if ((tid & 63) == 0) {
            sh[wave][0] = cnt; sh[wave][1] = sx; sh[wave][2] = sy;
        }
        __syncthreads();
        if (tid < 3)
            stats[id * 3 + tid] =
                sh[0][tid] + sh[1][tid] + sh[2][tid] + sh[3][tid];
    } else {
        // ---- keypoint path ----
        const int b = bid >> 5, c = bid & 31;
        const vf4* kb = (const vf4*)(kp + (size_t)b * NKP_CH * HW);

        int cnt[NPARTS], sx[NPARTS], sy[NPARTS];
#pragma unroll
        for (int p = 0; p < NPARTS; ++p) { cnt[p] = 0; sx[p] = 0; sy[p] = 0; }

#pragma unroll
        for (int j = 0; j < 2; ++j) {
            const int g = c * 512 + j * 256 + tid;
            vf4 s0, s1, s2, s3, s4, s5, s6, s7, v;
#define LD(K) kb[(K) * GROUPS + g]
            s0 = LD(0);
            v = LD(1); s0 += v;
            v = LD(2); s0 += v;
            v = LD(3); s0 += v;
            v = LD(4); s0 += v;
            v = LD(5); s1 = v; s2 = v;
            v = LD(6); s1 += v; s3 = v;
            v = LD(7); s2 += v;
            v = LD(8); s3 += v;
            v = LD(9); s2 += v;
            v = LD(10); s3 += v;
            v = LD(11); s1 += v; s4 = v;
            v = LD(12); s1 += v; s5 = v;
            v = LD(13); s4 += v;
            v = LD(14); s5 += v;
            v = LD(15); s4 += v; s6 = v;
            v = LD(16); s5 += v; s7 = v;
            v = LD(17); s6 += v;
            v = LD(18); s6 += v;
            v = LD(19); s6 += v;
            v = LD(20); s7 += v;
            v = LD(21); s7 += v;
            v = LD(22); s7 += v;
#undef LD
            const int base = g * 4;
            const int h = base >> 8, w0 = base & 255;
#define TALLY(P, S)                                                  \
            if ((S).x > 0.3f) { cnt[P]++; sx[P] += h; sy[P] += w0; }     \
            if ((S).y > 0.3f) { cnt[P]++; sx[P] += h; sy[P] += w0 + 1; } \
            if ((S).z > 0.3f) { cnt[P]++; sx[P] += h; sy[P] += w0 + 2; } \
            if ((S).w > 0.3f) { cnt[P]++; sx[P] += h; sy[P] += w0 + 3; }
            TALLY(0, s0) TALLY(1, s1) TALLY(2, s2) TALLY(3, s3)
            TALLY(4, s4) TALLY(5, s5) TALLY(6, s6) TALLY(7, s7)
#undef TALLY
        }

#pragma unroll
        for (int p = 0; p < NPARTS; ++p) {
#pragma unroll
            for (int off = 32; off; off >>= 1) {
                cnt[p] += __shfl_down(cnt[p], off);
                sx[p]  += __shfl_down(sx[p], off);
                sy[p]  += __shfl_down(sy[p], off);
            }
        }
        if ((tid & 63) == 0) {
#pragma unroll
            for (int p = 0; p < NPARTS; ++p) {
                sh[wave][p * 3 + 0] = cnt[p];
                sh[wave][p * 3 + 1] = sx[p];
                sh[wave][p * 3 + 2] = sy[p];
            }
        }
        __syncthreads();
        if (tid < NPARTS * 3)
            stats[KP_OFF + bid * 24 + tid] =
                sh[0][tid] + sh[1][tid] + sh[2][tid] + sh[3][tid];
    }
}

// ---------------------------------------------------------------------------
// Finisher: 1 block x 256 threads; thread t -> (b = t>>3, p = t&7).
// Sums the 2 mask half-plane partials and 32 kp chunk-partials, replays the
// reference's fp32 divisions, reduces the loss in double, writes the scalar.
// ---------------------------------------------------------------------------
__global__ __launch_bounds__(256) void finish_kernel(
    const int* __restrict__ stats, float* __restrict__ out) {
    const int t = threadIdx.x;
    const int b = t >> 3, p = t & 7;

    int cm = 0, sxm = 0, sym = 0;
#pragma unroll
    for (int half = 0; half < 2; ++half) {
        const int base = (t * 2 + half) * 3;
        cm  += stats[base + 0];
        sxm += stats[base + 1];
        sym += stats[base + 2];
    }

    int ck = 0, sxk = 0, syk = 0;
#pragma unroll
    for (int c = 0; c < 32; ++c) {
        const int base = KP_OFF + (b * 32 + c) * 24 + p * 3;
        ck  += stats[base + 0];
        sxk += stats[base + 1];
        syk += stats[base + 2];
    }

    const float cxm = (cm > 0 && sxm > 0) ? (float)sxm / (float)cm : 0.0f;
    const float cym = (cm > 0 && sym > 0) ? (float)sym / (float)cm : 0.0f;
    const float cxk = (ck > 0 && sxk > 0) ? (float)sxk / (float)ck : 0.0f;
    const float cyk = (ck > 0 && syk > 0) ? (float)syk / (float)ck : 0.0f;

    const bool code = (cxm == 0.0f) || (cym == 0.0f) ||
                      (cxk == 0.0f) || (cyk == 0.0f);
    double num = 0.0, nv = 0.0;
    if (!code) {
        const double dx = (double)cxm - (double)cxk;
        const double dy = (double)cym - (double)cyk;
        num = dx * dx + dy * dy;
        nv = 1.0;
    }
#pragma unroll
    for (int off = 32; off; off >>= 1) {
        num += __shfl_down(num, off);
        nv  += __shfl_down(nv, off);
    }
    __shared__ double sh[8];
    const int wave = t >> 6;
    if ((t & 63) == 0) { sh[wave * 2] = num; sh[wave * 2 + 1] = nv; }
    __syncthreads();
    if (t == 0) {
        const double N = sh[0] + sh[2] + sh[4] + sh[6];
        const double V = sh[1] + sh[3] + sh[5] + sh[7];
        out[0] = (float)(1e-5 * (N / (V * 2.0)));
    }
}

extern "C" void kernel_launch(void* const* d_in, const int* in_sizes, int n_in,
                              void* d_out, int out_size, void* d_ws, size_t ws_size,
                              hipStream_t stream) {
    const float* masks = (const float*)d_in[0];   // (32, 9, 256, 256) fp32
    const float* kp    = (const float*)d_in[1];   // (32, 23, 256, 256) fp32
    float* out = (float*)d_out;
    int* stats = (int*)d_ws;

    hipLaunchKernelGGL(stats_kernel, dim3(1536), dim3(256), 0, stream,
                       masks, kp, stats);
    hipLaunchKernelGGL(finish_kernel, dim3(1), dim3(256), 0, stream, stats, out);
}

// Round 4
// 283.857 us; speedup vs baseline: 1.1047x; 1.1047x over previous
//
#include <hip/hip_runtime.h>

// Problem constants
#define HW 65536            // 256*256
#define GROUPS 16384        // float4 groups per plane
#define NMASK_CH 9
#define NKP_CH 23
#define NPARTS 8
#define NB 32

// Workspace layout (ints):
//   [0, 1536)            mask half-plane partials: (b*8+p)*2+half -> *3 {cnt,sx,sy}
//   [1536, 1536+24576)   kp partials: 1536 + (b*32+c)*24 + p*3 + {cnt,sx,sy}
#define KP_OFF 1536

typedef float vf4 __attribute__((ext_vector_type(4)));

__device__ __forceinline__ vf4 ntload(const float* p) {
    return __builtin_nontemporal_load((const vf4*)p);
}

// ---------------------------------------------------------------------------
// Fused stats kernel, grid = 1536 blocks x 256 threads (6 blocks/CU).
//   blocks [0,1024):    kp chunk  (b = bid>>5, c = bid&31), 2 float4/thread,
//                       all 23 channels -> 8 part sums -> 24 integrals
//   blocks [1024,1536): mask half-plane (id = bid-1024: b = id>>4,
//                       p = (id>>1)&7, half = id&1), 32 float4/thread
// Per-block partials written to ws; no atomics, no zero-init needed.
// nt loads: streams bypass cache-fill contention with the harness's 736 MB
// ws-poison fill (R2 A/B evidence: nt 286 µs vs plain 314 µs).
// ---------------------------------------------------------------------------
__global__ __launch_bounds__(256) void stats_kernel(
    const float* __restrict__ masks, const float* __restrict__ kp,
    int* __restrict__ stats) {
    const int tid = threadIdx.x;
    const int bid = blockIdx.x;
    const int wave = tid >> 6;
    __shared__ int sh[4][NPARTS * 3];

    if (bid >= 1024) {
        // ---- mask path: half a plane per block ----
        const int id = bid - 1024;
        const int b = id >> 4, p = (id >> 1) & 7, half = id & 1;
        const float* plane = masks + ((size_t)b * NMASK_CH + 1 + p) * HW;
        int cnt = 0, sx = 0, sy = 0;
        const int gbase = half * 8192;
#pragma unroll 8
        for (int j = 0; j < 32; ++j) {
            const int g = gbase + tid + j * 256;
            const vf4 v = ntload(plane + (size_t)g * 4);
            const int base = g * 4;
            const int h = base >> 8, w0 = base & 255;
            if (v.x > 0.5f) { cnt++; sx += h; sy += w0; }
            if (v.y > 0.5f) { cnt++; sx += h; sy += w0 + 1; }
            if (v.z > 0.5f) { cnt++; sx += h; sy += w0 + 2; }
            if (v.w > 0.5f) { cnt++; sx += h; sy += w0 + 3; }
        }
#pragma unroll
        for (int off = 32; off; off >>= 1) {
            cnt += __shfl_down(cnt, off);
            sx  += __shfl_down(sx, off);
            sy  += __shfl_down(sy, off);
        }
        if ((tid & 63) == 0) {
            sh[wave][0] = cnt; sh[wave][1] = sx; sh[wave][2] = sy;
        }
        __syncthreads();
        if (tid < 3)
            stats[id * 3 + tid] =
                sh[0][tid] + sh[1][tid] + sh[2][tid] + sh[3][tid];
    } else {
        // ---- keypoint path ----
        const int b = bid >> 5, c = bid & 31;
        const float* kb = kp + (size_t)b * NKP_CH * HW;

        int cnt[NPARTS], sx[NPARTS], sy[NPARTS];
#pragma unroll
        for (int p = 0; p < NPARTS; ++p) { cnt[p] = 0; sx[p] = 0; sy[p] = 0; }

#pragma unroll
        for (int j = 0; j < 2; ++j) {
            const int g = c * 512 + j * 256 + tid;
            vf4 s0, s1, s2, s3, s4, s5, s6, s7, v;
#define LD(K) ntload(kb + (size_t)((K) * GROUPS + g) * 4)
            s0 = LD(0);
            v = LD(1); s0 += v;
            v = LD(2); s0 += v;
            v = LD(3); s0 += v;
            v = LD(4); s0 += v;
            v = LD(5); s1 = v; s2 = v;
            v = LD(6); s1 += v; s3 = v;
            v = LD(7); s2 += v;
            v = LD(8); s3 += v;
            v = LD(9); s2 += v;
            v = LD(10); s3 += v;
            v = LD(11); s1 += v; s4 = v;
            v = LD(12); s1 += v; s5 = v;
            v = LD(13); s4 += v;
            v = LD(14); s5 += v;
            v = LD(15); s4 += v; s6 = v;
            v = LD(16); s5 += v; s7 = v;
            v = LD(17); s6 += v;
            v = LD(18); s6 += v;
            v = LD(19); s6 += v;
            v = LD(20); s7 += v;
            v = LD(21); s7 += v;
            v = LD(22); s7 += v;
#undef LD
            const int base = g * 4;
            const int h = base >> 8, w0 = base & 255;
#define TALLY(P, S)                                                  \
            if ((S).x > 0.3f) { cnt[P]++; sx[P] += h; sy[P] += w0; }     \
            if ((S).y > 0.3f) { cnt[P]++; sx[P] += h; sy[P] += w0 + 1; } \
            if ((S).z > 0.3f) { cnt[P]++; sx[P] += h; sy[P] += w0 + 2; } \
            if ((S).w > 0.3f) { cnt[P]++; sx[P] += h; sy[P] += w0 + 3; }
            TALLY(0, s0) TALLY(1, s1) TALLY(2, s2) TALLY(3, s3)
            TALLY(4, s4) TALLY(5, s5) TALLY(6, s6) TALLY(7, s7)
#undef TALLY
        }

#pragma unroll
        for (int p = 0; p < NPARTS; ++p) {
#pragma unroll
            for (int off = 32; off; off >>= 1) {
                cnt[p] += __shfl_down(cnt[p], off);
                sx[p]  += __shfl_down(sx[p], off);
                sy[p]  += __shfl_down(sy[p], off);
            }
        }
        if ((tid & 63) == 0) {
#pragma unroll
            for (int p = 0; p < NPARTS; ++p) {
                sh[wave][p * 3 + 0] = cnt[p];
                sh[wave][p * 3 + 1] = sx[p];
                sh[wave][p * 3 + 2] = sy[p];
            }
        }
        __syncthreads();
        if (tid < NPARTS * 3)
            stats[KP_OFF + bid * 24 + tid] =
                sh[0][tid] + sh[1][tid] + sh[2][tid] + sh[3][tid];
    }
}

// ---------------------------------------------------------------------------
// Finisher: 1 block x 256 threads; thread t -> (b = t>>3, p = t&7).
// Sums the 2 mask half-plane partials and 32 kp chunk-partials, replays the
// reference's fp32 divisions, reduces the loss in double, writes the scalar.
// ---------------------------------------------------------------------------
__global__ __launch_bounds__(256) void finish_kernel(
    const int* __restrict__ stats, float* __restrict__ out) {
    const int t = threadIdx.x;
    const int b = t >> 3, p = t & 7;

    int cm = 0, sxm = 0, sym = 0;
#pragma unroll
    for (int half = 0; half < 2; ++half) {
        const int base = (t * 2 + half) * 3;
        cm  += stats[base + 0];
        sxm += stats[base + 1];
        sym += stats[base + 2];
    }

    int ck = 0, sxk = 0, syk = 0;
#pragma unroll
    for (int c = 0; c < 32; ++c) {
        const int base = KP_OFF + (b * 32 + c) * 24 + p * 3;
        ck  += stats[base + 0];
        sxk += stats[base + 1];
        syk += stats[base + 2];
    }

    const float cxm = (cm > 0 && sxm > 0) ? (float)sxm / (float)cm : 0.0f;
    const float cym = (cm > 0 && sym > 0) ? (float)sym / (float)cm : 0.0f;
    const float cxk = (ck > 0 && sxk > 0) ? (float)sxk / (float)ck : 0.0f;
    const float cyk = (ck > 0 && syk > 0) ? (float)syk / (float)ck : 0.0f;

    const bool code = (cxm == 0.0f) || (cym == 0.0f) ||
                      (cxk == 0.0f) || (cyk == 0.0f);
    double num = 0.0, nv = 0.0;
    if (!code) {
        const double dx = (double)cxm - (double)cxk;
        const double dy = (double)cym - (double)cyk;
        num = dx * dx + dy * dy;
        nv = 1.0;
    }
#pragma unroll
    for (int off = 32; off; off >>= 1) {
        num += __shfl_down(num, off);
        nv  += __shfl_down(nv, off);
    }
    __shared__ double sh[8];
    const int wave = t >> 6;
    if ((t & 63) == 0) { sh[wave * 2] = num; sh[wave * 2 + 1] = nv; }
    __syncthreads();
    if (t == 0) {
        const double N = sh[0] + sh[2] + sh[4] + sh[6];
        const double V = sh[1] + sh[3] + sh[5] + sh[7];
        out[0] = (float)(1e-5 * (N / (V * 2.0)));
    }
}

extern "C" void kernel_launch(void* const* d_in, const int* in_sizes, int n_in,
                              void* d_out, int out_size, void* d_ws, size_t ws_size,
                              hipStream_t stream) {
    const float* masks = (const float*)d_in[0];   // (32, 9, 256, 256) fp32
    const float* kp    = (const float*)d_in[1];   // (32, 23, 256, 256) fp32
    float* out = (float*)d_out;
    int* stats = (int*)d_ws;

    hipLaunchKernelGGL(stats_kernel, dim3(1536), dim3(256), 0, stream,
                       masks, kp, stats);
    hipLaunchKernelGGL(finish_kernel, dim3(1), dim3(256), 0, stream, stats, out);
}